// Round 5
// baseline (365.653 us; speedup 1.0000x reference)
//
#include <hip/hip_runtime.h>
#include <hip/hip_bf16.h>

#define BH   16
#define SEQ  2048
#define DH   64
#define TQ   16
#define TK   64
#define NT   (SEQ / TK)    // 32 k-tiles
#define KP   72            // LDS row stride in f16 (144 B)

typedef _Float16 f16;
using f32x4 = __attribute__((ext_vector_type(4))) float;
using f16x8 = __attribute__((ext_vector_type(8))) _Float16;
using f16x4 = __attribute__((ext_vector_type(4))) _Float16;

// lgkm-only barrier: does NOT drain vmcnt -> global prefetch stays in flight.
// All cross-wave data here moves through LDS, so lgkmcnt(0) + s_barrier is
// sufficient for correctness ("memory" clobber pins memory ops on their side).
#define BAR() asm volatile("s_waitcnt lgkmcnt(0)\n\ts_barrier" ::: "memory")

// One tile: consume LDS tile KT (QK+exp+P), stage tile KT+1 from reg set O,
// issue global loads for KT+2 into reg set S, PV on Vt[CUR].
#define TILE(KT, KS_, VS_, MS_, KO_, VO_, CUR)                                  \
  {                                                                             \
    const int4 mcur = MS_;   /* snapshot before reload overwrites */            \
    if ((KT) + 2 < NT) {                                                        \
      const int k0n = ((KT) + 2) * TK;                                          \
      const float* ksp = kb_ + (size_t)(k0n + kr) * DH;                         \
      _Pragma("unroll") for (int li = 0; li < 4; ++li)                          \
        KS_[li] = *(const f32x4*)(ksp + kc0 + li * 16);                         \
      _Pragma("unroll") for (int j = 0; j < 4; ++j)                             \
        VS_[j] = *(const f32x4*)(vb_ + (size_t)(k0n + vk + j) * DH + vd);       \
      MS_ = *(const int4*)(mask + mrow_ + k0n + w * 16 + g * 4);                \
    }                                                                           \
    f32x4 acc = {0.f, 0.f, 0.f, 0.f};                                           \
    { f16x8 a0 = *(const f16x8*)&Ks[w * 16 + lr][g * 8];                        \
      acc = __builtin_amdgcn_mfma_f32_16x16x32_f16(a0, qf0, acc, 0, 0, 0);      \
      f16x8 a1 = *(const f16x8*)&Ks[w * 16 + lr][32 + g * 8];                   \
      acc = __builtin_amdgcn_mfma_f32_16x16x32_f16(a1, qf1, acc, 0, 0, 0); }    \
    f16x4 pk;                                                                   \
    { const float p0 = mcur.x ? 0.f : __expf(acc[0] * 0.125f);                  \
      const float p1 = mcur.y ? 0.f : __expf(acc[1] * 0.125f);                  \
      const float p2 = mcur.z ? 0.f : __expf(acc[2] * 0.125f);                  \
      const float p3 = mcur.w ? 0.f : __expf(acc[3] * 0.125f);                  \
      lsum += (p0 + p1) + (p2 + p3);                                            \
      pk[0] = (f16)p0; pk[1] = (f16)p1; pk[2] = (f16)p2; pk[3] = (f16)p3; }     \
    *(f16x4*)(aph + (KT) * TK + w * 16 + g * 4) = pk;                           \
    *(f16x4*)&Ps[lr][w * 16 + g * 4] = pk;                                      \
    BAR();  /* A: Ps visible; all QK reads of Ks retired */                     \
    if ((KT) + 1 < NT) {                                                        \
      _Pragma("unroll") for (int li = 0; li < 4; ++li) {                        \
        f16x4 t = { (f16)KO_[li][0], (f16)KO_[li][1],                           \
                    (f16)KO_[li][2], (f16)KO_[li][3] };                         \
        *(f16x4*)&Ks[kr][kc0 + li * 16] = t;                                    \
      }                                                                         \
      _Pragma("unroll") for (int e = 0; e < 4; ++e) {                           \
        f16x4 t = { (f16)VO_[0][e], (f16)VO_[1][e],                             \
                    (f16)VO_[2][e], (f16)VO_[3][e] };                           \
        *(f16x4*)&Vt[(CUR) ^ 1][vd + e][vk] = t;                                \
      }                                                                         \
    }                                                                           \
    { f16x8 pa0 = *(const f16x8*)&Ps[lr][g * 8];                                \
      f16x8 vv0 = *(const f16x8*)&Vt[CUR][w * 16 + lr][g * 8];                  \
      oacc = __builtin_amdgcn_mfma_f32_16x16x32_f16(pa0, vv0, oacc, 0, 0, 0);   \
      f16x8 pa1 = *(const f16x8*)&Ps[lr][32 + g * 8];                           \
      f16x8 vv1 = *(const f16x8*)&Vt[CUR][w * 16 + lr][32 + g * 8];             \
      oacc = __builtin_amdgcn_mfma_f32_16x16x32_f16(pa1, vv1, oacc, 0, 0, 0); } \
    BAR();  /* B: staged tile KT+1 visible for next QK */                       \
  }

__global__ __launch_bounds__(256, 4)
void mha_pass_a(const float* __restrict__ key,
                const float* __restrict__ value,
                const float* __restrict__ query,
                const int*   __restrict__ mask,
                const float* __restrict__ qmask,
                float* __restrict__ out_res,
                float* __restrict__ out_attn)
{
  __shared__ f16 Ks[TK][KP];        //  9216 B (single buffer)
  __shared__ f16 Vt[2][DH][KP];     // 18432 B (double-buffered V^T [d][k])
  __shared__ f16 Ps[TQ][KP];        //  2304 B
  __shared__ f16 Qs[TQ][KP];        //  2304 B
  __shared__ float lred[4][TQ];
  __shared__ float rsc[TQ];

  const int tid  = threadIdx.x;
  const int lane = tid & 63;
  const int w    = tid >> 6;
  const int lr   = lane & 15;
  const int g    = lane >> 4;

  // XCD-chunked swizzle: each XCD owns 2 whole bh (K/V L2-resident)
  int flat = blockIdx.y * gridDim.x + blockIdx.x;            // 0..2047
  flat = (flat & 7) * ((BH * (SEQ / TQ)) / 8) + (flat >> 3); // bijective
  const int b  = flat >> 7;
  const int q0 = (flat & 127) * TQ;
  const size_t mbase = (size_t)b * SEQ * SEQ;
  const size_t mrow_ = mbase + (size_t)(q0 + lr) * SEQ;

  // staging coords
  const int kr  = tid >> 2;            // K row 0..63
  const int kc0 = (tid & 3) * 4;       // K col base (+ li*16)
  const int vk  = (tid & 15) * 4;      // V k-base (consecutive k per write row)
  const int vd  = (tid >> 4) * 4;      // V d-base

  const float* kb_ = key   + (size_t)b * SEQ * DH;
  const float* vb_ = value + (size_t)b * SEQ * DH;

  // ---- prologue: Q load + tile0 -> set A, tile1 -> set B ----
  const int qr = tid >> 4, qc = (tid & 15) * 4;
  f32x4 qv = *(const f32x4*)(query + ((size_t)(b * SEQ + q0 + qr)) * DH + qc);

  f32x4 kA[4], vA[4], kB[4], vB[4];
  int4  mA, mB;
  {
    const float* ksp = kb_ + (size_t)kr * DH;
    #pragma unroll
    for (int li = 0; li < 4; ++li) kA[li] = *(const f32x4*)(ksp + kc0 + li * 16);
    #pragma unroll
    for (int j = 0; j < 4; ++j)
      vA[j] = *(const f32x4*)(vb_ + (size_t)(vk + j) * DH + vd);
    mA = *(const int4*)(mask + mrow_ + w * 16 + g * 4);
  }
  {
    const float* ksp = kb_ + (size_t)(TK + kr) * DH;
    #pragma unroll
    for (int li = 0; li < 4; ++li) kB[li] = *(const f32x4*)(ksp + kc0 + li * 16);
    #pragma unroll
    for (int j = 0; j < 4; ++j)
      vB[j] = *(const f32x4*)(vb_ + (size_t)(TK + vk + j) * DH + vd);
    mB = *(const int4*)(mask + mrow_ + TK + w * 16 + g * 4);
  }
  { // stage Q
    f16x4 t = { (f16)qv[0], (f16)qv[1], (f16)qv[2], (f16)qv[3] };
    *(f16x4*)&Qs[qr][qc] = t;
  }
  { // stage tile 0 from set A
    #pragma unroll
    for (int li = 0; li < 4; ++li) {
      f16x4 t = { (f16)kA[li][0], (f16)kA[li][1], (f16)kA[li][2], (f16)kA[li][3] };
      *(f16x4*)&Ks[kr][kc0 + li * 16] = t;
    }
    #pragma unroll
    for (int e = 0; e < 4; ++e) {
      f16x4 t = { (f16)vA[0][e], (f16)vA[1][e], (f16)vA[2][e], (f16)vA[3][e] };
      *(f16x4*)&Vt[0][vd + e][vk] = t;
    }
  }
  BAR();

  const f16x8 qf0 = *(const f16x8*)&Qs[lr][g * 8];
  const f16x8 qf1 = *(const f16x8*)&Qs[lr][32 + g * 8];

  f16* aph = (f16*)(out_attn + mbase + (size_t)(q0 + lr) * SEQ) + 2048;

  f32x4 oacc = {0.f, 0.f, 0.f, 0.f};
  float lsum = 0.f;

  for (int kt = 0; kt < NT; kt += 2) {
    TILE(kt,     kA, vA, mA, kB, vB, 0);   // even tile: set A holds it
    TILE(kt + 1, kB, vB, mB, kA, vA, 1);   // odd tile: set B holds it
  }

  // ---- epilogue: l per q-row, scale, result write ----
  {
    float s = lsum;
    s += __shfl_xor(s, 16);
    s += __shfl_xor(s, 32);
    if (lane < 16) lred[w][lane] = s;
  }
  __syncthreads();
  if (tid < TQ) {
    const float l = lred[0][tid] + lred[1][tid] + lred[2][tid] + lred[3][tid];
    rsc[tid] = qmask[b * SEQ + q0 + tid] / fmaxf(l, 1e-37f);
  }
  __syncthreads();

  #pragma unroll
  for (int i = 0; i < 4; ++i)
    out_res[((size_t)(b * SEQ + q0 + g * 4 + i)) * DH + w * 16 + lr]
        = oacc[i] * rsc[g * 4 + i];
}

// ============================ Kernel B ============================
// One wave per row: read 4KB f16 strip, l = sum, write 8KB f32 row scaled.
__global__ __launch_bounds__(256)
void mha_pass_b(const float* __restrict__ qmask,
                float* __restrict__ out_attn)
{
  const int lane = threadIdx.x & 63;
  const int wv   = threadIdx.x >> 6;
  const int row  = blockIdx.x * 4 + wv;

  float* rowp = out_attn + (size_t)row * SEQ;
  const f16x8* src = (const f16x8*)((const f16*)rowp + 2048 + lane * 32);

  f16x8 v0 = src[0], v1 = src[1], v2 = src[2], v3 = src[3];

  float f[32];
  #pragma unroll
  for (int j = 0; j < 8; ++j) {
    f[j]      = (float)v0[j];
    f[8 + j]  = (float)v1[j];
    f[16 + j] = (float)v2[j];
    f[24 + j] = (float)v3[j];
  }
  float lsum = 0.f;
  #pragma unroll
  for (int j = 0; j < 32; ++j) lsum += f[j];
  #pragma unroll
  for (int off = 1; off < 64; off <<= 1) lsum += __shfl_xor(lsum, off);

  const float scale = qmask[row] / fmaxf(lsum, 1e-37f);

  float4* dst = (float4*)(rowp + lane * 32);
  #pragma unroll
  for (int m = 0; m < 8; ++m) {
    float4 o = { f[m * 4 + 0] * scale, f[m * 4 + 1] * scale,
                 f[m * 4 + 2] * scale, f[m * 4 + 3] * scale };
    dst[m] = o;
  }
}

extern "C" void kernel_launch(void* const* d_in, const int* in_sizes, int n_in,
                              void* d_out, int out_size, void* d_ws, size_t ws_size,
                              hipStream_t stream) {
  const float* key   = (const float*)d_in[0];
  const float* value = (const float*)d_in[1];
  const float* query = (const float*)d_in[2];
  const int*   mask  = (const int*)d_in[3];
  const float* qmask = (const float*)d_in[4];

  float* out_res  = (float*)d_out;                       // [16,2048,64]
  float* out_attn = out_res + (size_t)BH * SEQ * DH;     // [16,2048,2048]

  dim3 gridA(SEQ / TQ, BH);
  mha_pass_a<<<gridA, dim3(256), 0, stream>>>(
      key, value, query, mask, qmask, out_res, out_attn);

  dim3 gridB(BH * SEQ / 4);
  mha_pass_b<<<gridB, dim3(256), 0, stream>>>(qmask, out_attn);
}